// Round 2
// baseline (305.115 us; speedup 1.0000x reference)
//
#include <hip/hip_runtime.h>

// TransformerBlockQuantum: B=16384, S=8, E=8, H=8 (dk=1), NW=8, FFN=512.
// R2: wave-specialized block. 256 threads = 4 waves, 64 tokens/block.
//   wave 0: front (in_proj, attn via ds_swizzle, out_proj, quantum ring, LN1)
//           -> zf to LDS; keeps hh in regs.
//   all waves: FFN quarter (f-range uniform per wave -> scalar s_load weights,
//              8-wide f tiles -> contiguous s_load_dwordx8 for l1w AND l2w).
//   wave 0: cross-wave acc reduction via LDS, LN2, store.
// Grid 2048 blocks -> 32 waves/CU (100% occupancy) vs R1's 8 waves/CU (22%).

#define SWZ(v, J) __int_as_float(__builtin_amdgcn_ds_swizzle(__float_as_int(v), ((J) << 5) | 0x18))

__global__ __launch_bounds__(256, 8) void tbq_fused(
    const float* __restrict__ x,
    const float* __restrict__ ipw, const float* __restrict__ ipb,
    const float* __restrict__ opw, const float* __restrict__ opb,
    const float* __restrict__ rxa,
    const float* __restrict__ cw,  const float* __restrict__ cb,
    const float* __restrict__ g1,  const float* __restrict__ b1,
    const float* __restrict__ rxf,
    const float* __restrict__ l1w, const float* __restrict__ l1b,
    const float* __restrict__ l2w, const float* __restrict__ l2b,
    const float* __restrict__ g2,  const float* __restrict__ b2,
    float* __restrict__ out)
{
    __shared__ float lds_zf[64][9];        // stride 9 -> bank-conflict-free
    __shared__ float lds_acc[3][64][9];    // partials from waves 1..3

    const int lane = threadIdx.x & 63;
    const int wv   = threadIdx.x >> 6;
    const int tok  = blockIdx.x * 64 + lane;   // wave0's token; batch-aligned
    const int base = tok * 8;

    float hh[8];   // LN1 output, lives in wave0 regs through the FFN phase
    float zf[8];

    if (wv == 0) {
        // ---- load own x row (coalesced, 32B/lane) ----
        float xr[8];
        {
            const float4* px = reinterpret_cast<const float4*>(x + base);
            float4 a = px[0], b = px[1];
            xr[0] = a.x; xr[1] = a.y; xr[2] = a.z; xr[3] = a.w;
            xr[4] = b.x; xr[5] = b.y; xr[6] = b.z; xr[7] = b.w;
        }

        // ---- in_proj ----
        float q[8], k[8], v[8];
        #pragma unroll
        for (int e = 0; e < 8; ++e) {
            float aq = ipb[e], ak = ipb[8 + e], av = ipb[16 + e];
            #pragma unroll
            for (int d = 0; d < 8; ++d) {
                aq = fmaf(xr[d], ipw[e * 8 + d],       aq);
                ak = fmaf(xr[d], ipw[64 + e * 8 + d],  ak);
                av = fmaf(xr[d], ipw[128 + e * 8 + d], av);
            }
            q[e] = aq; k[e] = ak; v[e] = av;
        }

        // ---- attention per head (dk=1, scale=1) ----
        float orow[8];
        #pragma unroll
        for (int h = 0; h < 8; ++h) {
            const float kh = k[h], vh = v[h], qh = q[h];
            float kk[8], vv[8];
            kk[0] = SWZ(kh, 0); kk[1] = SWZ(kh, 1); kk[2] = SWZ(kh, 2); kk[3] = SWZ(kh, 3);
            kk[4] = SWZ(kh, 4); kk[5] = SWZ(kh, 5); kk[6] = SWZ(kh, 6); kk[7] = SWZ(kh, 7);
            vv[0] = SWZ(vh, 0); vv[1] = SWZ(vh, 1); vv[2] = SWZ(vh, 2); vv[3] = SWZ(vh, 3);
            vv[4] = SWZ(vh, 4); vv[5] = SWZ(vh, 5); vv[6] = SWZ(vh, 6); vv[7] = SWZ(vh, 7);
            float sc[8];
            #pragma unroll
            for (int j = 0; j < 8; ++j) sc[j] = qh * kk[j];
            float m = fmaxf(fmaxf(fmaxf(sc[0], sc[1]), fmaxf(sc[2], sc[3])),
                            fmaxf(fmaxf(sc[4], sc[5]), fmaxf(sc[6], sc[7])));
            float p[8];
            #pragma unroll
            for (int j = 0; j < 8; ++j) p[j] = __expf(sc[j] - m);
            float sum = ((p[0] + p[1]) + (p[2] + p[3])) + ((p[4] + p[5]) + (p[6] + p[7]));
            float ov = 0.f;
            #pragma unroll
            for (int j = 0; j < 8; ++j) ov = fmaf(p[j], vv[j], ov);
            orow[h] = ov * __builtin_amdgcn_rcpf(sum);
        }

        // ---- out_proj ----
        float ao[8];
        #pragma unroll
        for (int e = 0; e < 8; ++e) {
            float t = opb[e];
            #pragma unroll
            for (int h = 0; h < 8; ++h) t = fmaf(orow[h], opw[e * 8 + h], t);
            ao[e] = t;
        }

        // ---- quantum ring: cos + CNOT-ring Z ----
        float c[8];
        #pragma unroll
        for (int w = 0; w < 8; ++w) c[w] = __cosf(ao[w] + rxa[w]);
        float z[8];
        {
            float run = c[0];
            #pragma unroll
            for (int w = 1; w < 8; ++w) { run *= c[w]; z[w] = run; }
            float s17 = c[1];
            #pragma unroll
            for (int w = 2; w < 8; ++w) s17 *= c[w];
            z[0] = s17;
        }

        // ---- combine twice ----
        float saq[8];
        #pragma unroll
        for (int e = 0; e < 8; ++e) {
            float t = cb[e];
            #pragma unroll
            for (int w = 0; w < 8; ++w) t = fmaf(z[w], cw[e * 8 + w], t);
            saq[e] = ao[e] + t;
        }
        float at[8];
        #pragma unroll
        for (int e = 0; e < 8; ++e) {
            float t = cb[e];
            #pragma unroll
            for (int w = 0; w < 8; ++w) t = fmaf(saq[w], cw[e * 8 + w], t);
            at[e] = t;
        }

        // ---- LayerNorm1(x + attn_total) ----
        {
            float r[8]; float mean = 0.f;
            #pragma unroll
            for (int e = 0; e < 8; ++e) { r[e] = xr[e] + at[e]; mean += r[e]; }
            mean *= 0.125f;
            float var = 0.f;
            #pragma unroll
            for (int e = 0; e < 8; ++e) { float d = r[e] - mean; var = fmaf(d, d, var); }
            var *= 0.125f;
            float rs = __builtin_amdgcn_rsqf(var + 1e-5f);
            #pragma unroll
            for (int e = 0; e < 8; ++e) hh[e] = fmaf((r[e] - mean) * rs, g1[e], b1[e]);
        }

        // ---- zf = cos(h + rx_ffn); publish ----
        #pragma unroll
        for (int w = 0; w < 8; ++w) {
            zf[w] = __cosf(hh[w] + rxf[w]);
            lds_zf[lane][w] = zf[w];
        }
    }
    __syncthreads();

    if (wv != 0) {
        #pragma unroll
        for (int e = 0; e < 8; ++e) zf[e] = lds_zf[lane][e];
    }

    // ---- FFN quarter: f in [wv*128, wv*128+128), 8-wide tiles ----
    float acc[8];
    #pragma unroll
    for (int e = 0; e < 8; ++e) acc[e] = 0.f;

    const int f0 = wv * 128;
    #pragma unroll 2
    for (int t = 0; t < 16; ++t) {
        const int f = f0 + t * 8;
        float u[8];
        #pragma unroll
        for (int j = 0; j < 8; ++j) {
            float s = l1b[f + j];
            #pragma unroll
            for (int w = 0; w < 8; ++w) s = fmaf(zf[w], l1w[(f + j) * 8 + w], s);
            u[j] = fmaxf(s, 0.f);
        }
        #pragma unroll
        for (int e = 0; e < 8; ++e) {
            float s = acc[e];
            #pragma unroll
            for (int j = 0; j < 8; ++j) s = fmaf(u[j], l2w[e * 512 + f + j], s);
            acc[e] = s;
        }
    }

    if (wv != 0) {
        #pragma unroll
        for (int e = 0; e < 8; ++e) lds_acc[wv - 1][lane][e] = acc[e];
    }
    __syncthreads();

    // ---- wave 0: reduce partials, LN2, store ----
    if (wv == 0) {
        float r2[8]; float mean2 = 0.f;
        #pragma unroll
        for (int e = 0; e < 8; ++e) {
            float fo = l2b[e] + acc[e]
                     + lds_acc[0][lane][e] + lds_acc[1][lane][e] + lds_acc[2][lane][e];
            r2[e] = hh[e] + fo;
            mean2 += r2[e];
        }
        mean2 *= 0.125f;
        float var2 = 0.f;
        #pragma unroll
        for (int e = 0; e < 8; ++e) { float d = r2[e] - mean2; var2 = fmaf(d, d, var2); }
        var2 *= 0.125f;
        float rs2 = __builtin_amdgcn_rsqf(var2 + 1e-5f);
        float o[8];
        #pragma unroll
        for (int e = 0; e < 8; ++e) o[e] = fmaf((r2[e] - mean2) * rs2, g2[e], b2[e]);

        float4* po = reinterpret_cast<float4*>(out + base);
        po[0] = make_float4(o[0], o[1], o[2], o[3]);
        po[1] = make_float4(o[4], o[5], o[6], o[7]);
    }
}

extern "C" void kernel_launch(void* const* d_in, const int* in_sizes, int n_in,
                              void* d_out, int out_size, void* d_ws, size_t ws_size,
                              hipStream_t stream) {
    const float* x   = (const float*)d_in[0];
    const float* ipw = (const float*)d_in[1];
    const float* ipb = (const float*)d_in[2];
    const float* opw = (const float*)d_in[3];
    const float* opb = (const float*)d_in[4];
    const float* rxa = (const float*)d_in[5];
    const float* cw  = (const float*)d_in[6];
    const float* cb  = (const float*)d_in[7];
    const float* g1  = (const float*)d_in[8];
    const float* b1  = (const float*)d_in[9];
    const float* rxf = (const float*)d_in[10];
    const float* l1w = (const float*)d_in[11];
    const float* l1b = (const float*)d_in[12];
    const float* l2w = (const float*)d_in[13];
    const float* l2b = (const float*)d_in[14];
    const float* g2  = (const float*)d_in[15];
    const float* b2  = (const float*)d_in[16];
    float* out = (float*)d_out;

    const int tokens = 16384 * 8;              // 131072 tokens
    const int blocks = tokens / 64;            // 2048 blocks, 64 tokens each
    tbq_fused<<<dim3(blocks), dim3(256), 0, stream>>>(
        x, ipw, ipb, opw, opb, rxa, cw, cb, g1, b1, rxf,
        l1w, l1b, l2w, l2b, g2, b2, out);
}

// Round 4
// 78.915 us; speedup vs baseline: 3.8664x; 3.8664x over previous
//
#include <hip/hip_runtime.h>

// TransformerBlockQuantum: B=16384, S=8, E=8, H=8 (dk=1), NW=8, FFN=512.
// R4 = R3 with typedef fix (__fp16 ext vector, matching cvt_pkrtz return).
// (1) f16 v_dot2 FFN with prepacked weights in d_ws,
// (2) 2-way FFN split per token (front duplicated across wave pairs).
// Block = 256 thr = 4 waves, 128 tokens: waves 0,1 -> tokens [0,64) halves 0,1;
// waves 2,3 -> tokens [64,128). Grid 1024 -> 16 waves/CU.
// Weight reads wave-uniform -> s_load_dwordx8 (l2w pre-transposed).

typedef __fp16 half2v __attribute__((ext_vector_type(2)));

#define SWZ(v, J) __int_as_float(__builtin_amdgcn_ds_swizzle(__float_as_int(v), ((J) << 5) | 0x18))

__global__ __launch_bounds__(256) void pack_weights(
    const float* __restrict__ l1w, const float* __restrict__ l2w,
    half2v* __restrict__ wA, half2v* __restrict__ wBt)
{
    int t = blockIdx.x * 256 + threadIdx.x;      // 0..4095
    if (t < 2048) {
        // wA[f*4+p] = (l1w[f][2p], l1w[f][2p+1])  == linear pairs
        wA[t] = __builtin_amdgcn_cvt_pkrtz(l1w[2 * t], l1w[2 * t + 1]);
    } else {
        // wBt[i*8+e] = (l2w[e][2i], l2w[e][2i+1])  (transposed for dwordx8)
        int u = t - 2048;
        int i = u >> 3, e = u & 7;
        wBt[u] = __builtin_amdgcn_cvt_pkrtz(l2w[e * 512 + 2 * i],
                                            l2w[e * 512 + 2 * i + 1]);
    }
}

__global__ __launch_bounds__(256) void tbq_fused(
    const float* __restrict__ x,
    const float* __restrict__ ipw, const float* __restrict__ ipb,
    const float* __restrict__ opw, const float* __restrict__ opb,
    const float* __restrict__ rxa,
    const float* __restrict__ cw,  const float* __restrict__ cb,
    const float* __restrict__ g1,  const float* __restrict__ b1,
    const float* __restrict__ rxf,
    const half2v* __restrict__ wA, const float* __restrict__ l1b,
    const half2v* __restrict__ wBt, const float* __restrict__ l2b,
    const float* __restrict__ g2,  const float* __restrict__ b2,
    float* __restrict__ out)
{
    __shared__ float lds_acc[128][9];            // half-1 partials, pad 9

    const int lane = threadIdx.x & 63;
    const int wv   = threadIdx.x >> 6;
    const int half = wv & 1;
    const int tokLocal = ((wv >> 1) << 6) + lane;
    const int tok  = blockIdx.x * 128 + tokLocal;
    const int base = tok * 8;

    // ---- front: every wave computes it for its token (halves duplicate) ----
    float xr[8];
    {
        const float4* px = reinterpret_cast<const float4*>(x + base);
        float4 a = px[0], b = px[1];
        xr[0] = a.x; xr[1] = a.y; xr[2] = a.z; xr[3] = a.w;
        xr[4] = b.x; xr[5] = b.y; xr[6] = b.z; xr[7] = b.w;
    }

    float q[8], k[8], v[8];
    #pragma unroll
    for (int e = 0; e < 8; ++e) {
        float aq = ipb[e], ak = ipb[8 + e], av = ipb[16 + e];
        #pragma unroll
        for (int d = 0; d < 8; ++d) {
            aq = fmaf(xr[d], ipw[e * 8 + d],       aq);
            ak = fmaf(xr[d], ipw[64 + e * 8 + d],  ak);
            av = fmaf(xr[d], ipw[128 + e * 8 + d], av);
        }
        q[e] = aq; k[e] = ak; v[e] = av;
    }

    float orow[8];
    #pragma unroll
    for (int h = 0; h < 8; ++h) {
        const float kh = k[h], vh = v[h], qh = q[h];
        float kk[8], vv[8];
        kk[0] = SWZ(kh, 0); kk[1] = SWZ(kh, 1); kk[2] = SWZ(kh, 2); kk[3] = SWZ(kh, 3);
        kk[4] = SWZ(kh, 4); kk[5] = SWZ(kh, 5); kk[6] = SWZ(kh, 6); kk[7] = SWZ(kh, 7);
        vv[0] = SWZ(vh, 0); vv[1] = SWZ(vh, 1); vv[2] = SWZ(vh, 2); vv[3] = SWZ(vh, 3);
        vv[4] = SWZ(vh, 4); vv[5] = SWZ(vh, 5); vv[6] = SWZ(vh, 6); vv[7] = SWZ(vh, 7);
        float sc[8];
        #pragma unroll
        for (int j = 0; j < 8; ++j) sc[j] = qh * kk[j];
        float m = fmaxf(fmaxf(fmaxf(sc[0], sc[1]), fmaxf(sc[2], sc[3])),
                        fmaxf(fmaxf(sc[4], sc[5]), fmaxf(sc[6], sc[7])));
        float p[8];
        #pragma unroll
        for (int j = 0; j < 8; ++j) p[j] = __expf(sc[j] - m);
        float sum = ((p[0] + p[1]) + (p[2] + p[3])) + ((p[4] + p[5]) + (p[6] + p[7]));
        float ov = 0.f;
        #pragma unroll
        for (int j = 0; j < 8; ++j) ov = fmaf(p[j], vv[j], ov);
        orow[h] = ov * __builtin_amdgcn_rcpf(sum);
    }

    float ao[8];
    #pragma unroll
    for (int e = 0; e < 8; ++e) {
        float t = opb[e];
        #pragma unroll
        for (int h = 0; h < 8; ++h) t = fmaf(orow[h], opw[e * 8 + h], t);
        ao[e] = t;
    }

    float c[8];
    #pragma unroll
    for (int w = 0; w < 8; ++w) c[w] = __cosf(ao[w] + rxa[w]);
    float z[8];
    {
        float run = c[0];
        #pragma unroll
        for (int w = 1; w < 8; ++w) { run *= c[w]; z[w] = run; }
        float s17 = c[1];
        #pragma unroll
        for (int w = 2; w < 8; ++w) s17 *= c[w];
        z[0] = s17;
    }

    float saq[8];
    #pragma unroll
    for (int e = 0; e < 8; ++e) {
        float t = cb[e];
        #pragma unroll
        for (int w = 0; w < 8; ++w) t = fmaf(z[w], cw[e * 8 + w], t);
        saq[e] = ao[e] + t;
    }
    float at[8];
    #pragma unroll
    for (int e = 0; e < 8; ++e) {
        float t = cb[e];
        #pragma unroll
        for (int w = 0; w < 8; ++w) t = fmaf(saq[w], cw[e * 8 + w], t);
        at[e] = t;
    }

    float hh[8];
    {
        float r[8]; float mean = 0.f;
        #pragma unroll
        for (int e = 0; e < 8; ++e) { r[e] = xr[e] + at[e]; mean += r[e]; }
        mean *= 0.125f;
        float var = 0.f;
        #pragma unroll
        for (int e = 0; e < 8; ++e) { float d = r[e] - mean; var = fmaf(d, d, var); }
        var *= 0.125f;
        float rs = __builtin_amdgcn_rsqf(var + 1e-5f);
        #pragma unroll
        for (int e = 0; e < 8; ++e) hh[e] = fmaf((r[e] - mean) * rs, g1[e], b1[e]);
    }

    // ---- zf packed to half2 pairs ----
    half2v zp[4];
    #pragma unroll
    for (int w2 = 0; w2 < 4; ++w2) {
        float a0 = __cosf(hh[2 * w2]     + rxf[2 * w2]);
        float a1 = __cosf(hh[2 * w2 + 1] + rxf[2 * w2 + 1]);
        zp[w2] = __builtin_amdgcn_cvt_pkrtz(a0, a1);
    }

    // ---- FFN half: f-pair index i in [half*128, half*128+128) ----
    float acc[8];
    #pragma unroll
    for (int e = 0; e < 8; ++e) acc[e] = 0.f;

    const int i0 = half * 128;
    #pragma unroll 2
    for (int i = i0; i < i0 + 128; ++i) {
        const int f0 = 2 * i;
        float u0 = l1b[f0], u1 = l1b[f0 + 1];
        #pragma unroll
        for (int p = 0; p < 4; ++p) {
            u0 = __builtin_amdgcn_fdot2(zp[p], wA[f0 * 4 + p],     u0, false);
            u1 = __builtin_amdgcn_fdot2(zp[p], wA[f0 * 4 + 4 + p], u1, false);
        }
        u0 = fmaxf(u0, 0.f); u1 = fmaxf(u1, 0.f);
        half2v up = __builtin_amdgcn_cvt_pkrtz(u0, u1);
        #pragma unroll
        for (int e = 0; e < 8; ++e)
            acc[e] = __builtin_amdgcn_fdot2(up, wBt[i * 8 + e], acc[e], false);
    }

    // ---- combine halves, LN2, store ----
    if (half == 1) {
        #pragma unroll
        for (int e = 0; e < 8; ++e) lds_acc[tokLocal][e] = acc[e];
    }
    __syncthreads();

    if (half == 0) {
        float r2[8]; float mean2 = 0.f;
        #pragma unroll
        for (int e = 0; e < 8; ++e) {
            float fo = l2b[e] + acc[e] + lds_acc[tokLocal][e];
            r2[e] = hh[e] + fo;
            mean2 += r2[e];
        }
        mean2 *= 0.125f;
        float var2 = 0.f;
        #pragma unroll
        for (int e = 0; e < 8; ++e) { float d = r2[e] - mean2; var2 = fmaf(d, d, var2); }
        var2 *= 0.125f;
        float rs2 = __builtin_amdgcn_rsqf(var2 + 1e-5f);
        float o[8];
        #pragma unroll
        for (int e = 0; e < 8; ++e) o[e] = fmaf((r2[e] - mean2) * rs2, g2[e], b2[e]);

        float4* po = reinterpret_cast<float4*>(out + base);
        po[0] = make_float4(o[0], o[1], o[2], o[3]);
        po[1] = make_float4(o[4], o[5], o[6], o[7]);
    }
}

extern "C" void kernel_launch(void* const* d_in, const int* in_sizes, int n_in,
                              void* d_out, int out_size, void* d_ws, size_t ws_size,
                              hipStream_t stream) {
    const float* x   = (const float*)d_in[0];
    const float* ipw = (const float*)d_in[1];
    const float* ipb = (const float*)d_in[2];
    const float* opw = (const float*)d_in[3];
    const float* opb = (const float*)d_in[4];
    const float* rxa = (const float*)d_in[5];
    const float* cw  = (const float*)d_in[6];
    const float* cb  = (const float*)d_in[7];
    const float* g1  = (const float*)d_in[8];
    const float* b1  = (const float*)d_in[9];
    const float* rxf = (const float*)d_in[10];
    const float* l1w = (const float*)d_in[11];
    const float* l1b = (const float*)d_in[12];
    const float* l2w = (const float*)d_in[13];
    const float* l2b = (const float*)d_in[14];
    const float* g2  = (const float*)d_in[15];
    const float* b2  = (const float*)d_in[16];
    float* out = (float*)d_out;

    half2v* wA  = (half2v*)d_ws;                       // 2048 dwords
    half2v* wBt = (half2v*)((char*)d_ws + 8192);       // 2048 dwords

    pack_weights<<<dim3(16), dim3(256), 0, stream>>>(l1w, l2w, wA, wBt);

    const int tokens = 16384 * 8;                      // 131072
    const int blocks = tokens / 128;                   // 1024 blocks
    tbq_fused<<<dim3(blocks), dim3(256), 0, stream>>>(
        x, ipw, ipb, opw, opb, rxa, cw, cb, g1, b1, rxf,
        wA, l1b, wBt, l2b, g2, b2, out);
}

// Round 5
// 26.277 us; speedup vs baseline: 11.6113x; 3.0031x over previous
//
#include <hip/hip_runtime.h>

// TransformerBlockQuantum: B=16384, S=8, E=8, H=8 (dk=1), NW=8, FFN=512.
// R5: FFN via v_mfma_f32_16x16x16_f16 with swapped operands:
//   chunk nf (16 f-values):  D1[m=f][n=tok] = A1(W1,bias-row)·B1(zf^T,1-row)
//   relu+pack: D1 lane layout == B2 lane layout (k=f, n=tok) -> no shuffles
//   D2[m=e][n=tok] += A2(W2)·B2  accumulated over 32 chunks.
// Weights prepacked as A-fragments in d_ws (pack_frags), loaded once per wave
// into VGPRs (128 regs). 1 wave = 1 block = 64 tokens; front as R1 (per-lane,
// ds_swizzle attention); zf/ffn exchanged via per-wave LDS. No scalar-load
// dependency in the FFN inner loop at all.

typedef __fp16 half2v __attribute__((ext_vector_type(2)));
typedef __fp16 half4  __attribute__((ext_vector_type(4)));
typedef float  float4v __attribute__((ext_vector_type(4)));

#define SWZ(v, J) __int_as_float(__builtin_amdgcn_ds_swizzle(__float_as_int(v), ((J) << 5) | 0x18))

// A-frag layout for v_mfma_f32_16x16x16f16: lane l holds A[m=l&15][k=(l>>4)*4+j].
// A1[nf]: m = f_local (f = nf*16+m): k<8 -> W1[f][k]; k==8 -> l1b[f]; else 0.
// A2[nf]: m = e (<8, else zero row):  W2[e][nf*16+k].
__global__ __launch_bounds__(256) void pack_frags(
    const float* __restrict__ l1w, const float* __restrict__ l1b,
    const float* __restrict__ l2w,
    half4* __restrict__ a1ws, half4* __restrict__ a2ws)
{
    int t = blockIdx.x * 256 + threadIdx.x;   // 0..4095
    int u = t & 2047;
    int nf = u >> 6, l = u & 63;
    int m = l & 15, k0 = (l >> 4) * 4;
    half4 r;
    if (t < 2048) {
        int f = nf * 16 + m;
        #pragma unroll
        for (int j = 0; j < 4; ++j) {
            int k = k0 + j;
            float v = (k < 8) ? l1w[f * 8 + k] : ((k == 8) ? l1b[f] : 0.f);
            r[j] = (__fp16)v;
        }
        a1ws[nf * 64 + l] = r;
    } else {
        #pragma unroll
        for (int j = 0; j < 4; ++j) {
            int k = k0 + j;
            float v = (m < 8) ? l2w[m * 512 + nf * 16 + k] : 0.f;
            r[j] = (__fp16)v;
        }
        a2ws[nf * 64 + l] = r;
    }
}

__global__ __launch_bounds__(64, 2) void tbq_fused(
    const float* __restrict__ x,
    const float* __restrict__ ipw, const float* __restrict__ ipb,
    const float* __restrict__ opw, const float* __restrict__ opb,
    const float* __restrict__ rxa,
    const float* __restrict__ cw,  const float* __restrict__ cb,
    const float* __restrict__ g1,  const float* __restrict__ b1,
    const float* __restrict__ rxf,
    const half4* __restrict__ a1ws, const half4* __restrict__ a2ws,
    const float* __restrict__ l2b,
    const float* __restrict__ g2,  const float* __restrict__ b2,
    float* __restrict__ out)
{
    __shared__ half4 lds_zf[64][2];     // zf^T staging, 16B/token
    __shared__ float lds_f[64 * 10];    // ffn_out roundtrip, 40B stride (conflict-light)

    const int l    = threadIdx.x;       // 1 wave per block
    const int tok  = blockIdx.x * 64 + l;
    const int base = tok * 8;

    // ---- issue weight-fragment loads FIRST; they complete under the front ----
    half4 a1[32], a2[32];
    #pragma unroll
    for (int i = 0; i < 32; ++i) a1[i] = a1ws[i * 64 + l];
    #pragma unroll
    for (int i = 0; i < 32; ++i) a2[i] = a2ws[i * 64 + l];

    // ---- front (per-lane token, as R1) ----
    float xr[8];
    {
        const float4* px = reinterpret_cast<const float4*>(x + base);
        float4 a = px[0], b = px[1];
        xr[0] = a.x; xr[1] = a.y; xr[2] = a.z; xr[3] = a.w;
        xr[4] = b.x; xr[5] = b.y; xr[6] = b.z; xr[7] = b.w;
    }

    float q[8], k[8], v[8];
    #pragma unroll
    for (int e = 0; e < 8; ++e) {
        float aq = ipb[e], ak = ipb[8 + e], av = ipb[16 + e];
        #pragma unroll
        for (int d = 0; d < 8; ++d) {
            aq = fmaf(xr[d], ipw[e * 8 + d],       aq);
            ak = fmaf(xr[d], ipw[64 + e * 8 + d],  ak);
            av = fmaf(xr[d], ipw[128 + e * 8 + d], av);
        }
        q[e] = aq; k[e] = ak; v[e] = av;
    }

    float orow[8];
    #pragma unroll
    for (int h = 0; h < 8; ++h) {
        const float kh = k[h], vh = v[h], qh = q[h];
        float kk[8], vv[8];
        kk[0] = SWZ(kh, 0); kk[1] = SWZ(kh, 1); kk[2] = SWZ(kh, 2); kk[3] = SWZ(kh, 3);
        kk[4] = SWZ(kh, 4); kk[5] = SWZ(kh, 5); kk[6] = SWZ(kh, 6); kk[7] = SWZ(kh, 7);
        vv[0] = SWZ(vh, 0); vv[1] = SWZ(vh, 1); vv[2] = SWZ(vh, 2); vv[3] = SWZ(vh, 3);
        vv[4] = SWZ(vh, 4); vv[5] = SWZ(vh, 5); vv[6] = SWZ(vh, 6); vv[7] = SWZ(vh, 7);
        float sc[8];
        #pragma unroll
        for (int j = 0; j < 8; ++j) sc[j] = qh * kk[j];
        float m = fmaxf(fmaxf(fmaxf(sc[0], sc[1]), fmaxf(sc[2], sc[3])),
                        fmaxf(fmaxf(sc[4], sc[5]), fmaxf(sc[6], sc[7])));
        float p[8];
        #pragma unroll
        for (int j = 0; j < 8; ++j) p[j] = __expf(sc[j] - m);
        float sum = ((p[0] + p[1]) + (p[2] + p[3])) + ((p[4] + p[5]) + (p[6] + p[7]));
        float ov = 0.f;
        #pragma unroll
        for (int j = 0; j < 8; ++j) ov = fmaf(p[j], vv[j], ov);
        orow[h] = ov * __builtin_amdgcn_rcpf(sum);
    }

    float ao[8];
    #pragma unroll
    for (int e = 0; e < 8; ++e) {
        float t = opb[e];
        #pragma unroll
        for (int h = 0; h < 8; ++h) t = fmaf(orow[h], opw[e * 8 + h], t);
        ao[e] = t;
    }

    float c[8];
    #pragma unroll
    for (int w = 0; w < 8; ++w) c[w] = __cosf(ao[w] + rxa[w]);
    float z[8];
    {
        float run = c[0];
        #pragma unroll
        for (int w = 1; w < 8; ++w) { run *= c[w]; z[w] = run; }
        float s17 = c[1];
        #pragma unroll
        for (int w = 2; w < 8; ++w) s17 *= c[w];
        z[0] = s17;
    }

    float saq[8];
    #pragma unroll
    for (int e = 0; e < 8; ++e) {
        float t = cb[e];
        #pragma unroll
        for (int w = 0; w < 8; ++w) t = fmaf(z[w], cw[e * 8 + w], t);
        saq[e] = ao[e] + t;
    }
    float at[8];
    #pragma unroll
    for (int e = 0; e < 8; ++e) {
        float t = cb[e];
        #pragma unroll
        for (int w = 0; w < 8; ++w) t = fmaf(saq[w], cw[e * 8 + w], t);
        at[e] = t;
    }

    float hh[8];
    {
        float r[8]; float mean = 0.f;
        #pragma unroll
        for (int e = 0; e < 8; ++e) { r[e] = xr[e] + at[e]; mean += r[e]; }
        mean *= 0.125f;
        float var = 0.f;
        #pragma unroll
        for (int e = 0; e < 8; ++e) { float d = r[e] - mean; var = fmaf(d, d, var); }
        var *= 0.125f;
        float rs = __builtin_amdgcn_rsqf(var + 1e-5f);
        #pragma unroll
        for (int e = 0; e < 8; ++e) hh[e] = fmaf((r[e] - mean) * rs, g1[e], b1[e]);
    }

    // ---- zf = cos(h + rx_ffn), publish as half4 pair (zf^T source) ----
    {
        float zfv[8];
        #pragma unroll
        for (int w = 0; w < 8; ++w) zfv[w] = __cosf(hh[w] + rxf[w]);
        half2v p0 = __builtin_amdgcn_cvt_pkrtz(zfv[0], zfv[1]);
        half2v p1 = __builtin_amdgcn_cvt_pkrtz(zfv[2], zfv[3]);
        half2v p2 = __builtin_amdgcn_cvt_pkrtz(zfv[4], zfv[5]);
        half2v p3 = __builtin_amdgcn_cvt_pkrtz(zfv[6], zfv[7]);
        half4 lo, hi;
        lo.x = p0.x; lo.y = p0.y; lo.z = p1.x; lo.w = p1.y;
        hi.x = p2.x; hi.y = p2.y; hi.z = p3.x; hi.w = p3.y;
        lds_zf[l][0] = lo;
        lds_zf[l][1] = hi;
    }
    __syncthreads();

    // ---- FFN: 4 passes of 16 tokens, 32 chunks each ----
    const float4v zero4 = {0.f, 0.f, 0.f, 0.f};
    #pragma unroll 1
    for (int p = 0; p < 4; ++p) {
        // B1 fragment: k<8 -> zf[tok][k]; k==8 -> 1.0 (bias row); else 0
        half4 bz = {(__fp16)0.f, (__fp16)0.f, (__fp16)0.f, (__fp16)0.f};
        if (l < 32)      bz = lds_zf[p * 16 + (l & 15)][l >> 4];
        else if (l < 48) bz.x = (__fp16)1.f;

        float4v acc2 = zero4;
        #pragma unroll
        for (int nf = 0; nf < 32; ++nf) {
            float4v d1 = __builtin_amdgcn_mfma_f32_16x16x16f16(a1[nf], bz, zero4, 0, 0, 0);
            d1.x = fmaxf(d1.x, 0.f); d1.y = fmaxf(d1.y, 0.f);
            d1.z = fmaxf(d1.z, 0.f); d1.w = fmaxf(d1.w, 0.f);
            half2v q0 = __builtin_amdgcn_cvt_pkrtz(d1.x, d1.y);
            half2v q1 = __builtin_amdgcn_cvt_pkrtz(d1.z, d1.w);
            half4 bu;
            bu.x = q0.x; bu.y = q0.y; bu.z = q1.x; bu.w = q1.y;
            acc2 = __builtin_amdgcn_mfma_f32_16x16x16f16(a2[nf], bu, acc2, 0, 0, 0);
        }

        // D2 lane l (<32): out_ffn[tok = p*16 + (l&15)][e = (l>>4)*4 + r]
        if (l < 32) {
            float* dst = &lds_f[(p * 16 + (l & 15)) * 10 + (l >> 4) * 4];
            dst[0] = acc2.x; dst[1] = acc2.y; dst[2] = acc2.z; dst[3] = acc2.w;
        }
    }
    __syncthreads();

    // ---- residual + LN2 + store (owner lane) ----
    float r2[8]; float mean2 = 0.f;
    #pragma unroll
    for (int e = 0; e < 8; ++e) {
        float fo = lds_f[l * 10 + e] + l2b[e];
        r2[e] = hh[e] + fo;
        mean2 += r2[e];
    }
    mean2 *= 0.125f;
    float var2 = 0.f;
    #pragma unroll
    for (int e = 0; e < 8; ++e) { float d = r2[e] - mean2; var2 = fmaf(d, d, var2); }
    var2 *= 0.125f;
    float rs2 = __builtin_amdgcn_rsqf(var2 + 1e-5f);
    float o[8];
    #pragma unroll
    for (int e = 0; e < 8; ++e) o[e] = fmaf((r2[e] - mean2) * rs2, g2[e], b2[e]);

    float4* po = reinterpret_cast<float4*>(out + base);
    po[0] = make_float4(o[0], o[1], o[2], o[3]);
    po[1] = make_float4(o[4], o[5], o[6], o[7]);
}

extern "C" void kernel_launch(void* const* d_in, const int* in_sizes, int n_in,
                              void* d_out, int out_size, void* d_ws, size_t ws_size,
                              hipStream_t stream) {
    const float* x   = (const float*)d_in[0];
    const float* ipw = (const float*)d_in[1];
    const float* ipb = (const float*)d_in[2];
    const float* opw = (const float*)d_in[3];
    const float* opb = (const float*)d_in[4];
    const float* rxa = (const float*)d_in[5];
    const float* cw  = (const float*)d_in[6];
    const float* cb  = (const float*)d_in[7];
    const float* g1  = (const float*)d_in[8];
    const float* b1  = (const float*)d_in[9];
    const float* rxf = (const float*)d_in[10];
    const float* l1w = (const float*)d_in[11];
    const float* l1b = (const float*)d_in[12];
    const float* l2w = (const float*)d_in[13];
    const float* l2b = (const float*)d_in[14];
    const float* g2  = (const float*)d_in[15];
    const float* b2  = (const float*)d_in[16];
    float* out = (float*)d_out;

    half4* a1ws = (half4*)d_ws;                         // 32*64*8B = 16KB
    half4* a2ws = (half4*)((char*)d_ws + 16384);        // 16KB

    pack_frags<<<dim3(16), dim3(256), 0, stream>>>(l1w, l1b, l2w, a1ws, a2ws);

    const int tokens = 16384 * 8;                       // 131072
    tbq_fused<<<dim3(tokens / 64), dim3(64), 0, stream>>>(
        x, ipw, ipb, opw, opb, rxa, cw, cb, g1, b1, rxf,
        a1ws, a2ws, l2b, g2, b2, out);
}

// Round 6
// 26.003 us; speedup vs baseline: 11.7337x; 1.0105x over previous
//
#include <hip/hip_runtime.h>

// TransformerBlockQuantum: B=16384, S=8, E=8, H=8 (dk=1), NW=8, FFN=512.
// R6: single kernel. Each wave (64 tokens) gathers its own MFMA A-fragments
// from f32 weights at start (L2-resident, overlaps the front), then:
//   front per-lane (in_proj, ds_swizzle attention, out_proj, quantum, LN1)
//   FFN via v_mfma_f32_16x16x16_f16, pass-PAIRS interleaved for MFMA ILP:
//     d0/d1 = A1*bz0/bz1 ; relu+pack ; acc0/acc1 = A2*bu + acc
//   LN2 + store.
// No pack kernel, no d_ws. 2048 blocks x 64 threads (1 wave each).

typedef __fp16 half2v __attribute__((ext_vector_type(2)));
typedef __fp16 half4  __attribute__((ext_vector_type(4)));
typedef float  float4v __attribute__((ext_vector_type(4)));

#define SWZ(v, J) __int_as_float(__builtin_amdgcn_ds_swizzle(__float_as_int(v), ((J) << 5) | 0x18))

__global__ __launch_bounds__(64, 2) void tbq_fused(
    const float* __restrict__ x,
    const float* __restrict__ ipw, const float* __restrict__ ipb,
    const float* __restrict__ opw, const float* __restrict__ opb,
    const float* __restrict__ rxa,
    const float* __restrict__ cw,  const float* __restrict__ cb,
    const float* __restrict__ g1,  const float* __restrict__ b1,
    const float* __restrict__ rxf,
    const float* __restrict__ l1w, const float* __restrict__ l1b,
    const float* __restrict__ l2w, const float* __restrict__ l2b,
    const float* __restrict__ g2,  const float* __restrict__ b2,
    float* __restrict__ out)
{
    __shared__ half4 lds_zf[64][2];     // zf^T staging, 16B/token
    __shared__ float lds_f[64 * 10];    // ffn_out roundtrip, stride 10 floats

    const int l    = threadIdx.x;       // 1 wave per block
    const int tok  = blockIdx.x * 64 + l;
    const int base = tok * 8;

    // ---- gather A-fragments from f32 weights (L2-hot; overlaps front) ----
    // A-frag (16x16x16f16): lane l holds A[m=l&15][k=(l>>4)*4 + j], j=0..3.
    // A1[nf]: f = nf*16+m; k<8 -> W1[f][k]; k==8 -> l1b[f]; else 0.
    // A2[nf]: m<8 -> W2[m][nf*16+k]; else 0.
    const int m  = l & 15;
    const int k0 = (l >> 4) * 4;        // 0,4,8,12
    half4 a1[32], a2[32];
    const half4 zh = {(__fp16)0.f, (__fp16)0.f, (__fp16)0.f, (__fp16)0.f};

    if (l < 32) {                        // k0 = 0 or 4: W1 columns
        #pragma unroll
        for (int nf = 0; nf < 32; ++nf) {
            float4 w = *reinterpret_cast<const float4*>(l1w + (nf * 16 + m) * 8 + k0);
            half2v c0 = __builtin_amdgcn_cvt_pkrtz(w.x, w.y);
            half2v c1 = __builtin_amdgcn_cvt_pkrtz(w.z, w.w);
            half4 r; r.x = c0.x; r.y = c0.y; r.z = c1.x; r.w = c1.y;
            a1[nf] = r;
        }
    } else if (l < 48) {                 // k0 = 8: bias row at k==8
        #pragma unroll
        for (int nf = 0; nf < 32; ++nf) {
            half4 r = zh; r.x = (__fp16)l1b[nf * 16 + m];
            a1[nf] = r;
        }
    } else {                             // k0 = 12: zero pad
        #pragma unroll
        for (int nf = 0; nf < 32; ++nf) a1[nf] = zh;
    }

    if (m < 8) {
        #pragma unroll
        for (int nf = 0; nf < 32; ++nf) {
            float4 w = *reinterpret_cast<const float4*>(l2w + m * 512 + nf * 16 + k0);
            half2v c0 = __builtin_amdgcn_cvt_pkrtz(w.x, w.y);
            half2v c1 = __builtin_amdgcn_cvt_pkrtz(w.z, w.w);
            half4 r; r.x = c0.x; r.y = c0.y; r.z = c1.x; r.w = c1.y;
            a2[nf] = r;
        }
    } else {
        #pragma unroll
        for (int nf = 0; nf < 32; ++nf) a2[nf] = zh;
    }

    // ---- front (per-lane token) ----
    float xr[8];
    {
        const float4* px = reinterpret_cast<const float4*>(x + base);
        float4 a = px[0], b = px[1];
        xr[0] = a.x; xr[1] = a.y; xr[2] = a.z; xr[3] = a.w;
        xr[4] = b.x; xr[5] = b.y; xr[6] = b.z; xr[7] = b.w;
    }

    float q[8], k[8], v[8];
    #pragma unroll
    for (int e = 0; e < 8; ++e) {
        float aq = ipb[e], ak = ipb[8 + e], av = ipb[16 + e];
        #pragma unroll
        for (int d = 0; d < 8; ++d) {
            aq = fmaf(xr[d], ipw[e * 8 + d],       aq);
            ak = fmaf(xr[d], ipw[64 + e * 8 + d],  ak);
            av = fmaf(xr[d], ipw[128 + e * 8 + d], av);
        }
        q[e] = aq; k[e] = ak; v[e] = av;
    }

    float orow[8];
    #pragma unroll
    for (int h = 0; h < 8; ++h) {
        const float kh = k[h], vh = v[h], qh = q[h];
        float kk[8], vv[8];
        kk[0] = SWZ(kh, 0); kk[1] = SWZ(kh, 1); kk[2] = SWZ(kh, 2); kk[3] = SWZ(kh, 3);
        kk[4] = SWZ(kh, 4); kk[5] = SWZ(kh, 5); kk[6] = SWZ(kh, 6); kk[7] = SWZ(kh, 7);
        vv[0] = SWZ(vh, 0); vv[1] = SWZ(vh, 1); vv[2] = SWZ(vh, 2); vv[3] = SWZ(vh, 3);
        vv[4] = SWZ(vh, 4); vv[5] = SWZ(vh, 5); vv[6] = SWZ(vh, 6); vv[7] = SWZ(vh, 7);
        float sc[8];
        #pragma unroll
        for (int j = 0; j < 8; ++j) sc[j] = qh * kk[j];
        float mx = fmaxf(fmaxf(fmaxf(sc[0], sc[1]), fmaxf(sc[2], sc[3])),
                         fmaxf(fmaxf(sc[4], sc[5]), fmaxf(sc[6], sc[7])));
        float p[8];
        #pragma unroll
        for (int j = 0; j < 8; ++j) p[j] = __expf(sc[j] - mx);
        float sum = ((p[0] + p[1]) + (p[2] + p[3])) + ((p[4] + p[5]) + (p[6] + p[7]));
        float ov = 0.f;
        #pragma unroll
        for (int j = 0; j < 8; ++j) ov = fmaf(p[j], vv[j], ov);
        orow[h] = ov * __builtin_amdgcn_rcpf(sum);
    }

    float ao[8];
    #pragma unroll
    for (int e = 0; e < 8; ++e) {
        float t = opb[e];
        #pragma unroll
        for (int h = 0; h < 8; ++h) t = fmaf(orow[h], opw[e * 8 + h], t);
        ao[e] = t;
    }

    float c[8];
    #pragma unroll
    for (int w = 0; w < 8; ++w) c[w] = __cosf(ao[w] + rxa[w]);
    float z[8];
    {
        float run = c[0];
        #pragma unroll
        for (int w = 1; w < 8; ++w) { run *= c[w]; z[w] = run; }
        float s17 = c[1];
        #pragma unroll
        for (int w = 2; w < 8; ++w) s17 *= c[w];
        z[0] = s17;
    }

    float saq[8];
    #pragma unroll
    for (int e = 0; e < 8; ++e) {
        float t = cb[e];
        #pragma unroll
        for (int w = 0; w < 8; ++w) t = fmaf(z[w], cw[e * 8 + w], t);
        saq[e] = ao[e] + t;
    }
    float at[8];
    #pragma unroll
    for (int e = 0; e < 8; ++e) {
        float t = cb[e];
        #pragma unroll
        for (int w = 0; w < 8; ++w) t = fmaf(saq[w], cw[e * 8 + w], t);
        at[e] = t;
    }

    float hh[8];
    {
        float r[8]; float mean = 0.f;
        #pragma unroll
        for (int e = 0; e < 8; ++e) { r[e] = xr[e] + at[e]; mean += r[e]; }
        mean *= 0.125f;
        float var = 0.f;
        #pragma unroll
        for (int e = 0; e < 8; ++e) { float d = r[e] - mean; var = fmaf(d, d, var); }
        var *= 0.125f;
        float rs = __builtin_amdgcn_rsqf(var + 1e-5f);
        #pragma unroll
        for (int e = 0; e < 8; ++e) hh[e] = fmaf((r[e] - mean) * rs, g1[e], b1[e]);
    }

    // ---- zf = cos(h + rx_ffn), publish as half4 pair (zf^T source) ----
    {
        float zfv[8];
        #pragma unroll
        for (int w = 0; w < 8; ++w) zfv[w] = __cosf(hh[w] + rxf[w]);
        half2v p0 = __builtin_amdgcn_cvt_pkrtz(zfv[0], zfv[1]);
        half2v p1 = __builtin_amdgcn_cvt_pkrtz(zfv[2], zfv[3]);
        half2v p2 = __builtin_amdgcn_cvt_pkrtz(zfv[4], zfv[5]);
        half2v p3 = __builtin_amdgcn_cvt_pkrtz(zfv[6], zfv[7]);
        half4 lo, hi;
        lo.x = p0.x; lo.y = p0.y; lo.z = p1.x; lo.w = p1.y;
        hi.x = p2.x; hi.y = p2.y; hi.z = p3.x; hi.w = p3.y;
        lds_zf[l][0] = lo;
        lds_zf[l][1] = hi;
    }
    __syncthreads();

    // ---- FFN: 2 pass-pairs (2x16 tokens each), interleaved MFMA chains ----
    const float4v zero4 = {0.f, 0.f, 0.f, 0.f};
    #pragma unroll 1
    for (int pp = 0; pp < 2; ++pp) {
        const int p0 = pp * 2, p1 = pp * 2 + 1;
        // B1 fragment per pass: k<8 -> zf[tok][k]; k==8 -> 1.0; else 0
        half4 bz0 = zh, bz1 = zh;
        if (l < 32) {
            bz0 = lds_zf[p0 * 16 + m][l >> 4];
            bz1 = lds_zf[p1 * 16 + m][l >> 4];
        } else if (l < 48) {
            bz0.x = (__fp16)1.f; bz1.x = (__fp16)1.f;
        }

        float4v acc0 = zero4, acc1 = zero4;
        #pragma unroll
        for (int nf = 0; nf < 32; ++nf) {
            float4v d0 = __builtin_amdgcn_mfma_f32_16x16x16f16(a1[nf], bz0, zero4, 0, 0, 0);
            float4v d1 = __builtin_amdgcn_mfma_f32_16x16x16f16(a1[nf], bz1, zero4, 0, 0, 0);
            d0.x = fmaxf(d0.x, 0.f); d0.y = fmaxf(d0.y, 0.f);
            d0.z = fmaxf(d0.z, 0.f); d0.w = fmaxf(d0.w, 0.f);
            d1.x = fmaxf(d1.x, 0.f); d1.y = fmaxf(d1.y, 0.f);
            d1.z = fmaxf(d1.z, 0.f); d1.w = fmaxf(d1.w, 0.f);
            half2v q00 = __builtin_amdgcn_cvt_pkrtz(d0.x, d0.y);
            half2v q01 = __builtin_amdgcn_cvt_pkrtz(d0.z, d0.w);
            half2v q10 = __builtin_amdgcn_cvt_pkrtz(d1.x, d1.y);
            half2v q11 = __builtin_amdgcn_cvt_pkrtz(d1.z, d1.w);
            half4 bu0; bu0.x = q00.x; bu0.y = q00.y; bu0.z = q01.x; bu0.w = q01.y;
            half4 bu1; bu1.x = q10.x; bu1.y = q10.y; bu1.z = q11.x; bu1.w = q11.y;
            acc0 = __builtin_amdgcn_mfma_f32_16x16x16f16(a2[nf], bu0, acc0, 0, 0, 0);
            acc1 = __builtin_amdgcn_mfma_f32_16x16x16f16(a2[nf], bu1, acc1, 0, 0, 0);
        }

        // D2 lane l (<32): ffn_out[tok = p*16 + m][e = (l>>4)*4 + r]
        if (l < 32) {
            float* dst0 = &lds_f[(p0 * 16 + m) * 10 + (l >> 4) * 4];
            dst0[0] = acc0.x; dst0[1] = acc0.y; dst0[2] = acc0.z; dst0[3] = acc0.w;
            float* dst1 = &lds_f[(p1 * 16 + m) * 10 + (l >> 4) * 4];
            dst1[0] = acc1.x; dst1[1] = acc1.y; dst1[2] = acc1.z; dst1[3] = acc1.w;
        }
    }
    __syncthreads();

    // ---- residual + LN2 + store (owner lane) ----
    float r2[8]; float mean2 = 0.f;
    #pragma unroll
    for (int e = 0; e < 8; ++e) {
        float fo = lds_f[l * 10 + e] + l2b[e];
        r2[e] = hh[e] + fo;
        mean2 += r2[e];
    }
    mean2 *= 0.125f;
    float var2 = 0.f;
    #pragma unroll
    for (int e = 0; e < 8; ++e) { float d = r2[e] - mean2; var2 = fmaf(d, d, var2); }
    var2 *= 0.125f;
    float rs2 = __builtin_amdgcn_rsqf(var2 + 1e-5f);
    float o[8];
    #pragma unroll
    for (int e = 0; e < 8; ++e) o[e] = fmaf((r2[e] - mean2) * rs2, g2[e], b2[e]);

    float4* po = reinterpret_cast<float4*>(out + base);
    po[0] = make_float4(o[0], o[1], o[2], o[3]);
    po[1] = make_float4(o[4], o[5], o[6], o[7]);
}

extern "C" void kernel_launch(void* const* d_in, const int* in_sizes, int n_in,
                              void* d_out, int out_size, void* d_ws, size_t ws_size,
                              hipStream_t stream) {
    const float* x   = (const float*)d_in[0];
    const float* ipw = (const float*)d_in[1];
    const float* ipb = (const float*)d_in[2];
    const float* opw = (const float*)d_in[3];
    const float* opb = (const float*)d_in[4];
    const float* rxa = (const float*)d_in[5];
    const float* cw  = (const float*)d_in[6];
    const float* cb  = (const float*)d_in[7];
    const float* g1  = (const float*)d_in[8];
    const float* b1  = (const float*)d_in[9];
    const float* rxf = (const float*)d_in[10];
    const float* l1w = (const float*)d_in[11];
    const float* l1b = (const float*)d_in[12];
    const float* l2w = (const float*)d_in[13];
    const float* l2b = (const float*)d_in[14];
    const float* g2  = (const float*)d_in[15];
    const float* b2  = (const float*)d_in[16];
    float* out = (float*)d_out;

    const int tokens = 16384 * 8;                       // 131072
    tbq_fused<<<dim3(tokens / 64), dim3(64), 0, stream>>>(
        x, ipw, ipb, opw, opb, rxa, cw, cb, g1, b1, rxf,
        l1w, l1b, l2w, l2b, g2, b2, out);
}